// Round 10
// baseline (26.972 us; speedup 1.0000x reference)
//
#include <hip/hip_runtime.h>
#include <hip/hip_bf16.h>

// Polyphase resampler, up=2/down=3, 128-tap FIR, via bf16 MFMA.
//   out[2g]   = 2 * sum_u W_g[u]   * fe_r[u],  W_g[k]=x[3g-32+k]
//   out[2g+1] = 2 * sum_u W_g[u+2] * fo_r[u]
// MFMA 16x16x32 bf16, K=96; D[i][j] = out[2g0+16i+j].
//
// R10: wave-one-shot. Each wave = ONE 128-pair unit: stage private 2KB f32
// slice (2x global_load_lds, source-swizzled), per-wave vmcnt(0), 6 swizzled
// ds_read_b128, cvt->bf16, 3 MFMA, 4 stores, die. No barriers anywhere;
// 32 independent waves/CU keep ~40KB of loads in flight (Little's law needs
// ~9KB for 6.3TB/s). B-build hides in the load shadow. Slot swizzle
// s^((s>>3)&7) (involution) kills the 16-way f32-window bank conflict.

typedef __bf16 bf16x8 __attribute__((ext_vector_type(8)));
typedef float  f32x4  __attribute__((ext_vector_type(4)));

constexpr int BT  = 256;      // 4 waves; wave w handles unit 4*bid+w
constexpr int UP  = 128;      // output pairs per unit
constexpr int SLF = 512;      // f32 per wave-private slice (456 used)

__device__ __forceinline__ void gload_lds16(const float* g, float* l) {
    __builtin_amdgcn_global_load_lds(
        (const __attribute__((address_space(1))) void*)g,
        (__attribute__((address_space(3))) void*)l, 16, 0, 0);
}

__device__ __forceinline__ int swz(int s) {   // involutive 16B-slot swizzle
    return s ^ ((s >> 3) & 7);
}

__device__ __forceinline__ bf16x8 cvt8(float4 a, float4 b) {
    union { bf16x8 v; __hip_bfloat162 h[4]; } u;
    u.h[0] = __float22bfloat162_rn(make_float2(a.x, a.y));
    u.h[1] = __float22bfloat162_rn(make_float2(a.z, a.w));
    u.h[2] = __float22bfloat162_rn(make_float2(b.x, b.y));
    u.h[3] = __float22bfloat162_rn(make_float2(b.z, b.w));
    return u.v;
}

__global__ __launch_bounds__(BT) void resample23_mfma(
    const float* __restrict__ x,
    const float* __restrict__ filt,
    float* __restrict__ out,
    int N, int out_size, int n_units)
{
    __shared__ __align__(16) float xs[4][SLF];   // 8KB, wave-private slices

    const int t = threadIdx.x;
    const int w = t >> 6, l = t & 63;
    const int j = l & 15, q = l >> 4;

    const int  u  = blockIdx.x * 4 + w;          // this wave's unit
    const long F0 = 384L * u - 32;               // global f32 idx of slice[0]
    float* slice = xs[w];

    const bool active = (u < n_units);
    const bool fast   = active && (F0 >= 0) && (F0 + SLF <= (long)N);

    // ---- stage private slice (issue first; latency hides B-build) ----
    if (fast) {
        #pragma unroll
        for (int k = 0; k < 2; ++k) {
            int p = 64 * k + l;                  // phys 16B slot
            gload_lds16(x + F0 + 4 * swz(p), slice + 4 * p);
        }
    } else if (active) {
        #pragma unroll
        for (int k = 0; k < 8; ++k) {
            int i = 64 * k + l;                  // logical f32 index
            long gi = F0 + i;
            float v = (gi >= 0 && gi < (long)N) ? x[gi] : 0.0f;
            slice[4 * swz(i >> 2) + (i & 3)] = v;
        }
    }

    // ---- B fragments (independent of x loads; runs in load shadow) ----
    const int kq = q * 8, dlt = j >> 1, ph = j & 1;
    bf16x8 Bf[3];
    #pragma unroll
    for (int kc = 0; kc < 3; ++kc) {
        #pragma unroll
        for (int e = 0; e < 8; ++e) {
            int k = 32 * kc + kq + e;
            int v = k - 3 * dlt - 2 * ph;        // tap index
            float fv = (v >= 0 && v < 64) ? filt[(ph ? 126 : 127) - 2 * v] : 0.0f;
            Bf[kc][e] = (__bf16)fv;
        }
    }

    // per-wave fence: gload_lds (vmcnt) + boundary ds_writes (lgkmcnt)
    asm volatile("s_waitcnt vmcnt(0) lgkmcnt(0)" ::: "memory");
    __builtin_amdgcn_sched_barrier(0);

    if (active) {
        // ---- A fragments: 6 swizzled ds_read_b128 from own slice ----
        const int sb = 6 * j + 2 * q;            // logical slot base (24j+8q f32)
        float4 va[6];
        #pragma unroll
        for (int c = 0; c < 3; ++c) {
            #pragma unroll
            for (int h = 0; h < 2; ++h) {
                int s = sb + 8 * c + h;
                va[2 * c + h] = *reinterpret_cast<const float4*>(slice + 4 * swz(s));
            }
        }
        bf16x8 A0 = cvt8(va[0], va[1]);
        bf16x8 A1 = cvt8(va[2], va[3]);
        bf16x8 A2 = cvt8(va[4], va[5]);

        f32x4 acc = {0.0f, 0.0f, 0.0f, 0.0f};
        acc = __builtin_amdgcn_mfma_f32_16x16x32_bf16(A0, Bf[0], acc, 0, 0, 0);
        acc = __builtin_amdgcn_mfma_f32_16x16x32_bf16(A1, Bf[1], acc, 0, 0, 0);
        acc = __builtin_amdgcn_mfma_f32_16x16x32_bf16(A2, Bf[2], acc, 0, 0, 0);

        // D[i][j]: col=j, row=4q+r -> out[256u + 16*(4q+r) + j]
        const int obase = 256 * u + 64 * q + j;
        #pragma unroll
        for (int r = 0; r < 4; ++r) {
            int o = obase + 16 * r;
            if (o < out_size) out[o] = 2.0f * acc[r];
        }
    }
}

extern "C" void kernel_launch(void* const* d_in, const int* in_sizes, int n_in,
                              void* d_out, int out_size, void* d_ws, size_t ws_size,
                              hipStream_t stream)
{
    const float* x    = (const float*)d_in[0];
    const float* filt = (const float*)d_in[1];
    float* out        = (float*)d_out;
    const int N       = in_sizes[0];

    const int n_pairs = (out_size + 1) / 2;
    const int n_units = (n_pairs + UP - 1) / UP;
    const int blocks  = (n_units + 3) / 4;
    resample23_mfma<<<blocks, BT, 0, stream>>>(x, filt, out, N, out_size, n_units);
}